// Round 1
// baseline (65.765 us; speedup 1.0000x reference)
//
#include <hip/hip_runtime.h>

// Problem constants (from reference setup_inputs).
#define KBINS 161
#define TFRAMES 2000

// One block per time frame t. Threads 0..K-1 act as both "source row i"
// (staging + S computation) and "output row j" (gather).
//
// Math: out[j,t] = sum_i w(i,j,t) * x[i,t]
//   wide_i (am_i > 1): w = relu(am_i - |j-i|) / S_i,  S_i = sum_j relu(am_i - |j-i|)
//   else:              w = (i == j)
// The reference's /am^2 cancels under the row normalization.
__global__ __launch_bounds__(256) void m_noise_smooth_kernel(
    const float* __restrict__ m,   // (K, T, 1)
    const float* __restrict__ x,   // (1, 1, K, T)
    float* __restrict__ out) {     // (1, 1, K, T)
  const int t = blockIdx.x;
  const int tid = threadIdx.x;

  __shared__ float s_am[KBINS];     // |m[i,t]|
  __shared__ float s_scale[KBINS];  // wide ? 1/S : 0 (0 flags the delta branch)
  __shared__ float s_x[KBINS];      // x[i,t]
  __shared__ float s_red[256];      // block max reduction of am

  float am = 0.0f;
  if (tid < KBINS) {
    const int i = tid;
    am = fabsf(m[i * TFRAMES + t]);
    s_am[i] = am;
    s_x[i] = x[i * TFRAMES + t];

    // Edge-truncated triangle mass: S = am + sum_{d=1}^{floor(am)} (am-d)*cnt
    float S = am;  // d = 0 term (j == i, always in range)
    int dmax = (int)am;
    if (dmax > KBINS - 1) dmax = KBINS - 1;
    for (int d = 1; d <= dmax; ++d) {
      int cnt = (i - d >= 0) + (i + d < KBINS);
      S += (am - (float)d) * (float)cnt;
    }
    const bool wide = am > 1.0f;
    s_scale[i] = wide ? (1.0f / S) : 0.0f;  // S >= am > 1 when wide, safe
  }

  // Block-wide max(am) -> gather radius. Also serves as the barrier between
  // LDS staging above and the gather below.
  s_red[tid] = am;  // inactive threads contribute 0
  __syncthreads();
  for (int s = 128; s > 0; s >>= 1) {
    if (tid < s) s_red[tid] = fmaxf(s_red[tid], s_red[tid + s]);
    __syncthreads();
  }
  const float maxam = s_red[0];

  if (tid < KBINS) {
    const int j = tid;
    int R = (int)ceilf(maxam);
    if (R > KBINS - 1) R = KBINS - 1;
    const int lo = (j - R > 0) ? (j - R) : 0;
    const int hi = (j + R < KBINS - 1) ? (j + R) : (KBINS - 1);

    // Delta branch: non-wide source i contributes x[i,t] only at j == i.
    float acc = (s_scale[j] == 0.0f) ? s_x[j] : 0.0f;

    for (int i = lo; i <= hi; ++i) {
      // lanes read consecutive LDS addresses (i = j + const) -> conflict-free
      const float d = fabsf((float)(j - i));
      const float w = fmaxf(s_am[i] - d, 0.0f) * s_scale[i];
      acc = fmaf(w, s_x[i], acc);
    }
    out[j * TFRAMES + t] = acc;
  }
}

extern "C" void kernel_launch(void* const* d_in, const int* in_sizes, int n_in,
                              void* d_out, int out_size, void* d_ws, size_t ws_size,
                              hipStream_t stream) {
  const float* m = (const float*)d_in[0];  // (K, T, 1) fp32
  const float* x = (const float*)d_in[1];  // (1, 1, K, T) fp32
  // d_in[2] = input_length (unused by the reference math)
  float* out = (float*)d_out;              // (1, 1, K, T) fp32

  m_noise_smooth_kernel<<<TFRAMES, 256, 0, stream>>>(m, x, out);
}